// Round 8
// baseline (7588.340 us; speedup 1.0000x reference)
//
#include <hip/hip_runtime.h>
#include <hip/hip_bf16.h>
#include <hip/hip_fp16.h>
#include <cmath>

// Problem constants
#define BATCH 16
#define SEQ 256
#define EMBED 512
#define HIDDEN 1024
#define GATES 4096       // 4*HIDDEN
#define VOCAB 32000
#define MROWS 4096       // BATCH*SEQ
#define LOGITS_SZ 131072000  // 16*256*32000

typedef unsigned short ushort_t;
typedef unsigned int uint_t;
typedef __attribute__((ext_vector_type(8))) __bf16 bf16x8;
typedef __attribute__((ext_vector_type(4))) float f32x4;

// ---------------- embedding gather ----------------
__global__ void embed_kernel(const int* __restrict__ x, const float* __restrict__ emb,
                             float* __restrict__ X0) {
    int r = blockIdx.x;            // r = s*16 + b
    int s = r >> 4, b = r & 15;
    int tok = x[b * SEQ + s];
    const float4* src = (const float4*)(emb + (size_t)tok * EMBED);
    float4* dst = (float4*)(X0 + (size_t)r * EMBED);
    for (int i = threadIdx.x; i < EMBED / 4; i += blockDim.x) dst[i] = src[i];
}

// ---------------- transpose + gate-interleave + BLOCK-TILED fp16 pack ----------------
// W [4096][1024] (rows = gate*1024 + j) -> T[cb][kOff+k][c16] fp16, where
// col' = j*4 + gate, cb = col'>>4, c16 = col'&15, k-stride 16, block stride kTot*16.
__global__ void transpose_f16_tiled(const float* __restrict__ W, ushort_t* __restrict__ T,
                                    int kOff, int kTot) {
    __shared__ float tile[32][33];
    int c0 = blockIdx.x * 32, r0 = blockIdx.y * 32;   // c0: k range, r0: W-row range
    int tx = threadIdx.x & 31, ty = threadIdx.x >> 5; // 256 threads: ty 0..7
    for (int i = ty; i < 32; i += 8)
        tile[i][tx] = W[(size_t)(r0 + i) * HIDDEN + (c0 + tx)];
    __syncthreads();
    int g = r0 >> 10, j0 = r0 & 1023;
    for (int i = ty; i < 32; i += 8) {
        int colp = (j0 + tx) * 4 + g;
        int cb = colp >> 4, c16 = colp & 15;
        int k = kOff + c0 + i;
        T[((size_t)cb * kTot + k) * 16 + c16] =
            __half_as_ushort(__float2half_rn(tile[tx][i]));
    }
}

// ---------------- fp32 -> bf16 hi/lo split: X[r][RL] -> Y[r][2*RL] ----------------
__device__ __forceinline__ unsigned f2bf(float f) {
    unsigned u = __float_as_uint(f);
    return (u + 0x7FFFu + ((u >> 16) & 1u)) >> 16;   // RNE
}

__global__ __launch_bounds__(256) void conv_hilo(const float* __restrict__ X,
                                                 ushort_t* __restrict__ Y, int RL) {
    size_t r = blockIdx.x;
    int k4 = threadIdx.x * 4;
    if (k4 >= RL) return;
    float4 v = *(const float4*)(X + r * RL + k4);
    unsigned h0 = f2bf(v.x), h1 = f2bf(v.y), h2 = f2bf(v.z), h3 = f2bf(v.w);
    unsigned l0 = f2bf(v.x - __uint_as_float(h0 << 16));
    unsigned l1 = f2bf(v.y - __uint_as_float(h1 << 16));
    unsigned l2 = f2bf(v.z - __uint_as_float(h2 << 16));
    unsigned l3 = f2bf(v.w - __uint_as_float(h3 << 16));
    uint2 hv, lv;
    hv.x = h0 | (h1 << 16); hv.y = h2 | (h3 << 16);
    lv.x = l0 | (l1 << 16); lv.y = l2 | (l3 << 16);
    *(uint2*)(Y + r * 2 * RL + k4) = hv;
    *(uint2*)(Y + r * 2 * RL + RL + k4) = lv;
}

// ---------------- split-bf16 MFMA GEMM ----------------
// C = A32 @ B32^T + b1 + b2 via up-to-3 passes: Ah*Bh (+ Al*Bh) (+ Ah*Bl), fp32 acc.
// flags bit0: row perm r -> (r&15)*SEQ + (r>>4); bit1: col perm c -> (c&1023)*4 + (c>>10)
__global__ __launch_bounds__(256) void gemm_bf16_mfma(
    const ushort_t* __restrict__ A, const ushort_t* __restrict__ B,
    const float* __restrict__ b1, const float* __restrict__ b2,
    float* __restrict__ C, int Kel, int ldc, int nBase, int flags, int segs) {
    __shared__ __align__(16) ushort_t As[128 * 32];
    __shared__ __align__(16) ushort_t Bs[128 * 32];
    int tid = threadIdx.x;
    int lane = tid & 63, wave = tid >> 6;
    int wm = wave >> 1, wn = wave & 1;

    // bijective XCD swizzle (nwg % 8 == 0 in all uses)
    int nx = gridDim.x;
    int nwg = nx * gridDim.y;
    int orig = blockIdx.y * nx + blockIdx.x;
    int s = (orig & 7) * (nwg >> 3) + (orig >> 3);
    int bm = s % nx, bn = s / nx;

    f32x4 acc[4][4];
#pragma unroll
    for (int m = 0; m < 4; m++)
#pragma unroll
        for (int n = 0; n < 4; n++) acc[m][n] = (f32x4){0.f, 0.f, 0.f, 0.f};

    int srow = tid >> 1;            // 0..127: staged row
    int skh = (tid & 1) * 16;       // ushort k-offset 0/16
    const ushort_t* Abase = A + (size_t)(bm * 128 + srow) * (2 * Kel) + skh;
    const ushort_t* Bbase = B + (size_t)(bn * 128 + srow) * (2 * Kel) + skh;
    int lr = lane & 15;
    int lk = (lane >> 4) * 8;

#pragma unroll 1
    for (int seg = 0; seg < segs; seg++) {
        int aoff = (seg == 1) ? Kel : 0;     // seg0: Ah*Bh, seg1: Al*Bh, seg2: Ah*Bl
        int boff = (seg == 2) ? Kel : 0;
        for (int k0 = 0; k0 < Kel; k0 += 32) {
            uint4 a0 = *(const uint4*)(Abase + aoff + k0);
            uint4 a1 = *(const uint4*)(Abase + aoff + k0 + 8);
            uint4 b0 = *(const uint4*)(Bbase + boff + k0);
            uint4 b1v = *(const uint4*)(Bbase + boff + k0 + 8);
            __syncthreads();
            *(uint4*)(As + srow * 32 + skh) = a0;
            *(uint4*)(As + srow * 32 + skh + 8) = a1;
            *(uint4*)(Bs + srow * 32 + skh) = b0;
            *(uint4*)(Bs + srow * 32 + skh + 8) = b1v;
            __syncthreads();
            bf16x8 af[4], bfv[4];
#pragma unroll
            for (int m = 0; m < 4; m++)
                af[m] = *(const bf16x8*)(As + (wm * 64 + m * 16 + lr) * 32 + lk);
#pragma unroll
            for (int n = 0; n < 4; n++)
                bfv[n] = *(const bf16x8*)(Bs + (wn * 64 + n * 16 + lr) * 32 + lk);
#pragma unroll
            for (int m = 0; m < 4; m++)
#pragma unroll
                for (int n = 0; n < 4; n++)
                    acc[m][n] = __builtin_amdgcn_mfma_f32_16x16x32_bf16(
                        af[m], bfv[n], acc[m][n], 0, 0, 0);
        }
    }

    // epilogue: C/D layout col=lane&15, row=(lane>>4)*4+j
    int lq = lane >> 4;
#pragma unroll
    for (int n = 0; n < 4; n++) {
        int c = bn * 128 + wn * 64 + n * 16 + lr;
        float bb = (b1 ? b1[c] : 0.f) + (b2 ? b2[c] : 0.f);
        int cw = (flags & 2) ? ((c & 1023) * 4 + (c >> 10)) : c;
#pragma unroll
        for (int m = 0; m < 4; m++) {
#pragma unroll
            for (int j = 0; j < 4; j++) {
                int r = bm * 128 + wm * 64 + m * 16 + lq * 4 + j;
                int orow = (flags & 1) ? ((r & 15) * SEQ + (r >> 4)) : r;
                C[(size_t)orow * ldc + nBase + cw] = acc[m][n][j] + bb;
            }
        }
    }
}

// ---------------- z-staggered dual-layer fused LSTM step ----------------
// grid (256 cb, 2 z), 512 threads, 2 blocks/CU co-resident.
// z=0: layer0 step t=L   gates = G0[t] + h0(t) @ Wt0          (K=1024)
// z=1: layer1 step t=L-1 gates = bsum1 + [o0(t);h1(t)] @ Wc1  (K=2048)
// h state fp16, HT layout [z][parity][1024 j][16 b]. Weights block-tiled fp16.
// Block owns 16 gate-interleaved cols' = 4 hidden units -> local state update.
__global__ __launch_bounds__(512) void lstm_fused2(
    const ushort_t* __restrict__ Wt0,   // [256][1024][16] fp16
    const ushort_t* __restrict__ Wc1,   // [256][2048][16] fp16 ([W_ih1;W_hh1])
    const float* __restrict__ G0,       // [4096 rows][4096] interleaved (incl. biases)
    const float* __restrict__ bsum1,    // [4096] interleaved b_ih1+b_hh1
    ushort_t* __restrict__ HT,          // [2][2][16384] fp16
    float* __restrict__ c_state,        // [2][16][1024]
    float* __restrict__ Hseq1,          // [4096 rows][1024]
    int L) {
    __shared__ __align__(16) ushort_t hs[32768];   // 64 KB fp16 h (pt overlaid later)
    __shared__ float gv[256];
    int z = blockIdx.y;
    int t = L - z;
    if (t < 0 || t > SEQ - 1) return;
    int cb = blockIdx.x;
    int tid = threadIdx.x;

    // stage h (fp16) into LDS
    if (z == 0) {
        const uint_t* sA = (const uint_t*)(HT + (L & 1) * 16384);
        for (int i = tid; i < 8192; i += 512) ((uint_t*)hs)[i] = sA[i];
    } else {
        const uint_t* sA = (const uint_t*)(HT + (L & 1) * 16384);              // o0(t)
        const uint_t* sB = (const uint_t*)(HT + 32768 + ((L + 1) & 1) * 16384); // h1 state
        for (int i = tid; i < 8192; i += 512) {
            ((uint_t*)hs)[i] = sA[i];
            ((uint_t*)hs)[8192 + i] = sB[i];
        }
    }
    __syncthreads();

    int c4 = tid & 3;
    int b = (tid >> 2) & 15;
    int kg = tid >> 6;                  // 0..7
    int kspan = (z == 0) ? 128 : 256;
    const ushort_t* wp = (z == 0 ? Wt0 + ((size_t)cb * 1024 + kg * 128) * 16
                                 : Wc1 + ((size_t)cb * 2048 + kg * 256) * 16) + c4 * 4;
    const ushort_t* hp = hs + kg * kspan * 16 + b;

    float4 acc = {0.f, 0.f, 0.f, 0.f};
#pragma unroll 8
    for (int kk = 0; kk < kspan; kk++) {
        uint2 u = *(const uint2*)(wp + kk * 16);
        float2 f01 = __half22float2(*(const __half2*)&u.x);
        float2 f23 = __half22float2(*(const __half2*)&u.y);
        float h = __half2float(*(const __half*)(hp + kk * 16));
        acc.x += h * f01.x; acc.y += h * f01.y;
        acc.z += h * f23.x; acc.w += h * f23.y;
    }
    __syncthreads();                     // all hs reads done; hs region now reusable
    float* pt = (float*)hs;              // [8][256] partials, 8 KB overlay
    *(float4*)&pt[kg * 256 + b * 16 + c4 * 4] = acc;
    __syncthreads();

    if (tid < 256) {                     // reduce 8 K-chunks + add base gates
        int c16 = tid & 15, bb = tid >> 4;
        float g = (z == 0) ? G0[((size_t)(t * BATCH + bb)) * GATES + cb * 16 + c16]
                           : bsum1[cb * 16 + c16];
#pragma unroll
        for (int q = 0; q < 8; q++) g += pt[q * 256 + bb * 16 + c16];
        gv[tid] = g;                     // gv[bb*16 + c16]
    }
    __syncthreads();

    if (tid < 64) {                      // state update: 4 j x 16 b
        int jl = tid & 3, bb = tid >> 2;
        float4 g4 = *(const float4*)&gv[bb * 16 + jl * 4];   // i,f,g,o
        float ig = 1.f / (1.f + __expf(-g4.x));
        float fg = 1.f / (1.f + __expf(-g4.y));
        float gg = tanhf(g4.z);
        float og = 1.f / (1.f + __expf(-g4.w));
        int j = cb * 4 + jl;
        int ci = z * 16384 + bb * 1024 + j;
        float c = fg * c_state[ci] + ig * gg;
        c_state[ci] = c;
        float h = og * tanhf(c);
        int par = (t + 1) & 1;
        HT[z * 32768 + par * 16384 + j * BATCH + bb] =
            __half_as_ushort(__float2half_rn(h));
        if (z == 1) Hseq1[((size_t)(t * BATCH + bb)) * HIDDEN + j] = h;
    }
}

// ---------------- init & tails ----------------
__global__ void init_state2(const float* __restrict__ h0, const float* __restrict__ c0,
                            const float* __restrict__ b_ih1, const float* __restrict__ b_hh1,
                            float* __restrict__ c_ws, ushort_t* __restrict__ HT,
                            float* __restrict__ bsum1) {
    int gid = blockIdx.x * 256 + threadIdx.x;  // 32768
    c_ws[gid] = c0[gid];
    int l = gid >> 14, b = (gid >> 10) & 15, j = gid & 1023;
    HT[l * 32768 + j * BATCH + b] = __half_as_ushort(__float2half_rn(h0[gid])); // parity 0
    if (gid < 4096) {
        int orig = (gid & 3) * 1024 + (gid >> 2);
        bsum1[gid] = b_ih1[orig] + b_hh1[orig];
    }
}

__global__ void write_tails2(const ushort_t* __restrict__ HT, const float* __restrict__ c_ws,
                             float* __restrict__ out) {
    int gid = blockIdx.x * 256 + threadIdx.x;  // 32768
    int l = gid >> 14, b = (gid >> 10) & 15, j = gid & 1023;
    out[LOGITS_SZ + gid] =
        __half2float(__ushort_as_half(HT[l * 32768 + j * BATCH + b]));  // final parity 0
    out[LOGITS_SZ + 32768 + gid] = c_ws[gid];
}

// ---------------- launch ----------------
extern "C" void kernel_launch(void* const* d_in, const int* in_sizes, int n_in,
                              void* d_out, int out_size, void* d_ws, size_t ws_size,
                              hipStream_t stream) {
    const int* x = (const int*)d_in[0];
    const float* h0 = (const float*)d_in[1];
    const float* c0 = (const float*)d_in[2];
    const float* emb = (const float*)d_in[3];
    const float* W_ih0 = (const float*)d_in[4];
    const float* W_hh0 = (const float*)d_in[5];
    const float* b_ih0 = (const float*)d_in[6];
    const float* b_hh0 = (const float*)d_in[7];
    const float* W_ih1 = (const float*)d_in[8];
    const float* W_hh1 = (const float*)d_in[9];
    const float* b_ih1 = (const float*)d_in[10];
    const float* b_hh1 = (const float*)d_in[11];
    const float* fc_W = (const float*)d_in[12];
    const float* fc_b = (const float*)d_in[13];
    float* out = (float*)d_out;
    float* ws = (float*)d_ws;

    // workspace layout (float offsets)
    const size_t OFF_WT0  = 0;          // [256][1024][16] fp16 = 2,097,152 fl
    const size_t OFF_WC1  = 2097152;    // [256][2048][16] fp16 = 4,194,304 fl
    const size_t OFF_X0   = 6291456;    // 4096*512  = 2,097,152
    const size_t OFF_G    = 8388608;    // 4096*4096 = 16,777,216 (ends 25,165,824)
    const size_t OFF_H1S  = 25165824;   // 4096*1024 = 4,194,304 (ends 29,360,128)
    const size_t OFF_C    = 29360128;   // 32,768
    const size_t OFF_HT   = 29392896;   // 65,536 halfs = 32,768 fl
    const size_t OFF_BSUM = 29425664;   // 4,096

    ushort_t* HTp = (ushort_t*)(ws + OFF_HT);

    // phase overlays (regions dead at time of use):
    ushort_t* XHL = (ushort_t*)(ws + OFF_H1S);                 // [4096][1024] us
    ushort_t* WIH0HL = (ushort_t*)(ws + OFF_H1S + 2097152);    // [4096][1024] us
    ushort_t* Whl = (ushort_t*)ws;                             // [16000][2048] us (FC)
    ushort_t* Ahl = (ushort_t*)(ws + 16384000);                // [4096][2048] us (FC)

    init_state2<<<128, 256, 0, stream>>>(h0, c0, b_ih1, b_hh1,
                                         ws + OFF_C, HTp, ws + OFF_BSUM);
    embed_kernel<<<MROWS, 128, 0, stream>>>(x, emb, ws + OFF_X0);
    transpose_f16_tiled<<<dim3(32, 128), 256, 0, stream>>>(W_hh0, (ushort_t*)(ws + OFF_WT0), 0, 1024);
    transpose_f16_tiled<<<dim3(32, 128), 256, 0, stream>>>(W_ih1, (ushort_t*)(ws + OFF_WC1), 0, 2048);
    transpose_f16_tiled<<<dim3(32, 128), 256, 0, stream>>>(W_hh1, (ushort_t*)(ws + OFF_WC1), 1024, 2048);

    // layer-0 input projection: G = X0 @ W_ih0^T + b_ih0 + b_hh0 (gate-interleaved, 3-seg)
    conv_hilo<<<MROWS, 256, 0, stream>>>(ws + OFF_X0, XHL, EMBED);
    conv_hilo<<<GATES, 256, 0, stream>>>(W_ih0, WIH0HL, EMBED);
    gemm_bf16_mfma<<<dim3(32, 32), 256, 0, stream>>>(
        XHL, WIH0HL, b_ih0, b_hh0, ws + OFF_G, EMBED, GATES, 0, 2, 3);

    // z-staggered dual-layer recurrence: 257 launches cover both layers
    for (int L = 0; L <= SEQ; L++) {
        lstm_fused2<<<dim3(256, 2), 512, 0, stream>>>(
            (const ushort_t*)(ws + OFF_WT0), (const ushort_t*)(ws + OFF_WC1),
            ws + OFF_G, ws + OFF_BSUM, HTp, ws + OFF_C, ws + OFF_H1S, L);
    }

    // FC via split-bf16 MFMA (2-seg): logits[b][s][v]
    conv_hilo<<<MROWS, 256, 0, stream>>>(ws + OFF_H1S, Ahl, HIDDEN);
    for (int half = 0; half < 2; half++) {
        conv_hilo<<<16000, 256, 0, stream>>>(fc_W + (size_t)half * 16000 * HIDDEN, Whl, HIDDEN);
        gemm_bf16_mfma<<<dim3(32, 125), 256, 0, stream>>>(
            Ahl, Whl, fc_b, nullptr, out, HIDDEN, VOCAB, half * 16000, 1, 2);
    }

    write_tails2<<<128, 256, 0, stream>>>(HTp, ws + OFF_C, out);
}